// Round 1
// baseline (421.978 us; speedup 1.0000x reference)
//
#include <hip/hip_runtime.h>

#define NCLS 88
#define DHW (96 * 96 * 96)            // 884736
#define TPB 256
#define BLOCKS_PER_B (DHW / TPB)      // 3456, exact
#define SMOOTH 1e-5f

// ws layout (floats):
// [0   .. 176)  inter[b*88+c]
// [176 .. 352)  pred_o[b*88+c]
// [352 .. 528)  ground_o[b*88+c]  (counts)
// [528]         ce_sum
#define WS_FLOATS 529

__device__ __forceinline__ float wave_reduce_sum(float v) {
#pragma unroll
    for (int i = 1; i < 64; i <<= 1)
        v += __shfl_xor(v, i, 64);
    return v;
}

__global__ __launch_bounds__(TPB)
void seg_loss_main(const float* __restrict__ pred, const int* __restrict__ tgt,
                   float* __restrict__ ws) {
    __shared__ float s_inter[NCLS];
    __shared__ float s_pred[NCLS];
    __shared__ float s_cnt[NCLS];
    __shared__ float s_ce;

    const int tid = threadIdx.x;
    const int b  = blockIdx.x / BLOCKS_PER_B;
    const int sp = (blockIdx.x % BLOCKS_PER_B) * TPB + tid;
    const float* p = pred + (size_t)b * NCLS * DHW + sp;

    if (tid < NCLS) { s_inter[tid] = 0.f; s_pred[tid] = 0.f; s_cnt[tid] = 0.f; }
    if (tid == 0) s_ce = 0.f;

    const int t = tgt[(size_t)b * DHW + sp];
    const bool valid = (t != -1);
    const int tc = valid ? t : 0;

    // ---- single pass: load all 88 logits into registers (static indexing only) ----
    float x[NCLS];
#pragma unroll
    for (int c = 0; c < NCLS; ++c) x[c] = p[(size_t)c * DHW];

    if (!valid) {
#pragma unroll
        for (int c = 0; c < NCLS; ++c) x[c] = 0.f;   // pred_m = pred * vf
    }

    float m = x[0];
#pragma unroll
    for (int c = 1; c < NCLS; ++c) m = fmaxf(m, x[c]);

    float xt = 0.f;
    float s1 = 0.f;
#pragma unroll
    for (int c = 0; c < NCLS; ++c) {
        const float raw = x[c];
        if (c == tc) xt = raw;            // c compile-time, tc runtime -> cndmask
        const float e = __expf(raw - m);
        x[c] = e;
        s1 += e;
    }
    const float inv = 1.0f / s1;
    const float lse = m + __logf(s1);

    __syncthreads();   // LDS accumulators zeroed

    // pred_o: per-class sum of p^2 (wave butterfly, 1 LDS atomic per wave per class)
#pragma unroll
    for (int c = 0; c < NCLS; ++c) {
        const float pc = x[c] * inv;
        float v2 = pc * pc;
        v2 = wave_reduce_sum(v2);
        if ((tid & 63) == 0) atomicAdd(&s_pred[c], v2);
    }

    // CE: nll over valid voxels
    float nll = valid ? (lse - xt) : 0.f;
    nll = wave_reduce_sum(nll);
    if ((tid & 63) == 0) atomicAdd(&s_ce, nll);

    // inter + ground_o: scatter to target class
    if (valid) {
        const float pt = __expf(xt - m) * inv;
        atomicAdd(&s_inter[tc], pt);
        atomicAdd(&s_cnt[tc], 1.f);
    }

    __syncthreads();

    if (tid < NCLS) {
        atomicAdd(&ws[0 * 176 + b * NCLS + tid], s_inter[tid]);
        atomicAdd(&ws[1 * 176 + b * NCLS + tid], s_pred[tid]);
        atomicAdd(&ws[2 * 176 + b * NCLS + tid], s_cnt[tid]);
    }
    if (tid == 0) atomicAdd(&ws[528], s_ce);
}

__global__ __launch_bounds__(TPB)
void seg_loss_final(const float* __restrict__ ws, float* __restrict__ out) {
    const int tid = threadIdx.x;
    float dice = 0.f, cnt = 0.f;
    if (tid < 2 * NCLS) {
        const float I = ws[tid];
        const float P = ws[176 + tid];
        const float G = ws[352 + tid];
        dice = 1.f - (2.f * I + SMOOTH) / (G + P + SMOOTH);
        cnt  = G;
    }
    dice = wave_reduce_sum(dice);
    cnt  = wave_reduce_sum(cnt);

    __shared__ float sd[4], sc[4];
    const int w = tid >> 6, l = tid & 63;
    if (l == 0) { sd[w] = dice; sc[w] = cnt; }
    __syncthreads();
    if (tid == 0) {
        const float D  = sd[0] + sd[1] + sd[2] + sd[3];
        const float Cn = sc[0] + sc[1] + sc[2] + sc[3];
        const float ce = ws[528] / fmaxf(Cn, 1.0f);
        out[0] = 0.4f * ce + 0.6f * (D / 176.f);
    }
}

extern "C" void kernel_launch(void* const* d_in, const int* in_sizes, int n_in,
                              void* d_out, int out_size, void* d_ws, size_t ws_size,
                              hipStream_t stream) {
    const float* pred = (const float*)d_in[0];
    const int*   tgt  = (const int*)d_in[1];
    float* ws = (float*)d_ws;

    hipMemsetAsync(d_ws, 0, WS_FLOATS * sizeof(float), stream);
    seg_loss_main<<<2 * BLOCKS_PER_B, TPB, 0, stream>>>(pred, tgt, ws);
    seg_loss_final<<<1, TPB, 0, stream>>>(ws, (float*)d_out);
}

// Round 3
// 310.624 us; speedup vs baseline: 1.3585x; 1.3585x over previous
//
#include <hip/hip_runtime.h>

#define NCLS 88
#define DHW (96 * 96 * 96)            // 884736
#define TPB 256
#define BLOCKS_PER_B (DHW / TPB)      // 3456, exact
#define SMOOTH 1e-5f
#define NCHUNK 11                     // 11 chunks of 8 classes

// ws layout (floats):
// [0   .. 176)  inter[b*88+c]
// [176 .. 352)  pred_o[b*88+c]
// [352 .. 528)  ground_o[b*88+c]  (counts)
// [528]         ce_sum
#define WS_FLOATS 529

typedef __fp16 h2 __attribute__((ext_vector_type(2)));
union H2I { h2 h; int i; };

__device__ __forceinline__ float wave_reduce_sum(float v) {
#pragma unroll
    for (int i = 1; i < 64; i <<= 1)
        v += __shfl_xor(v, i, 64);
    return v;
}

__device__ __forceinline__ h2 wave_reduce_h2(h2 v) {
#pragma unroll
    for (int i = 1; i < 64; i <<= 1) {
        H2I u; u.h = v;
        u.i = __shfl_xor(u.i, i, 64);
        v = v + u.h;                   // v_pk_add_f16
    }
    return v;
}

__global__ __launch_bounds__(TPB)
void seg_loss_main(const float* __restrict__ pred, const int* __restrict__ tgt,
                   float* __restrict__ ws) {
    __shared__ float s_inter[NCLS];
    __shared__ float s_pred[NCLS];
    __shared__ float s_cnt[NCLS];
    __shared__ float s_ce;

    const int tid = threadIdx.x;
    const int b  = blockIdx.x / BLOCKS_PER_B;
    const int sp = (blockIdx.x % BLOCKS_PER_B) * TPB + tid;
    const float* p = pred + (size_t)b * NCLS * DHW + sp;

    if (tid < NCLS) { s_inter[tid] = 0.f; s_pred[tid] = 0.f; s_cnt[tid] = 0.f; }
    if (tid == 0) s_ce = 0.f;

    const int t = tgt[(size_t)b * DHW + sp];
    const bool valid = (t != -1);
    const int tc = valid ? t : 0;
    const float vf = valid ? 1.0f : 0.0f;

    // ---- pass A: single global read, online max/sum, exp stored packed-fp16 ----
    float m = -1e30f, s1 = 0.f, xt = 0.f;
    float mch[NCHUNK];
    h2 eh[NCHUNK * 4];

#pragma unroll
    for (int k = 0; k < NCHUNK; ++k) {
        float x[8];
#pragma unroll
        for (int i = 0; i < 8; ++i) x[i] = p[(size_t)(k * 8 + i) * DHW];
#pragma unroll
        for (int i = 0; i < 8; ++i) {
            if (k * 8 + i == tc) xt = x[i];   // compile-time c vs runtime tc -> cndmask
            x[i] *= vf;                       // pred_m = pred * vf
        }
        const float cm = fmaxf(fmaxf(fmaxf(x[0], x[1]), fmaxf(x[2], x[3])),
                               fmaxf(fmaxf(x[4], x[5]), fmaxf(x[6], x[7])));
        const float nm = fmaxf(m, cm);
        const float sc = __expf(m - nm);
        float e[8];
#pragma unroll
        for (int i = 0; i < 8; ++i) e[i] = __expf(x[i] - nm);
        s1 = s1 * sc + (((e[0] + e[1]) + (e[2] + e[3])) + ((e[4] + e[5]) + (e[6] + e[7])));
        m = nm;
        mch[k] = nm;
#pragma unroll
        for (int i = 0; i < 4; ++i)
            eh[k * 4 + i] = __builtin_amdgcn_cvt_pkrtz(e[2 * i], e[2 * i + 1]);
    }

    const float inv = 1.0f / s1;
    const float lse = m + __logf(s1);

    __syncthreads();   // LDS accumulators zeroed

    // ---- CE ----
    float nll = valid ? (lse - xt) : 0.f;
    nll = wave_reduce_sum(nll);
    if ((tid & 63) == 0) atomicAdd(&s_ce, nll);

    // ---- inter + ground_o ----
    if (valid) {
        const float pt = __expf(xt - m) * inv;
        atomicAdd(&s_inter[tc], pt);
        atomicAdd(&s_cnt[tc], 1.f);
    }

    // ---- pass B: per-class sum of p^2 from packed exps (no global re-read) ----
#pragma unroll
    for (int k = 0; k < NCHUNK; ++k) {
        const float cs = __expf(mch[k] - m) * inv;
        const __fp16 csh = (__fp16)cs;
        const h2 cs2 = { csh, csh };
#pragma unroll
        for (int i = 0; i < 4; ++i) {
            h2 pp = eh[k * 4 + i] * cs2;     // v_pk_mul_f16
            h2 sq = pp * pp;
            sq = wave_reduce_h2(sq);
            if ((tid & 63) == 0) {
                atomicAdd(&s_pred[k * 8 + 2 * i],     (float)sq.x);
                atomicAdd(&s_pred[k * 8 + 2 * i + 1], (float)sq.y);
            }
        }
    }

    __syncthreads();

    if (tid < NCLS) {
        atomicAdd(&ws[0 * 176 + b * NCLS + tid], s_inter[tid]);
        atomicAdd(&ws[1 * 176 + b * NCLS + tid], s_pred[tid]);
        atomicAdd(&ws[2 * 176 + b * NCLS + tid], s_cnt[tid]);
    }
    if (tid == 0) atomicAdd(&ws[528], s_ce);
}

__global__ __launch_bounds__(TPB)
void seg_loss_final(const float* __restrict__ ws, float* __restrict__ out) {
    const int tid = threadIdx.x;
    float dice = 0.f, cnt = 0.f;
    if (tid < 2 * NCLS) {
        const float I = ws[tid];
        const float P = ws[176 + tid];
        const float G = ws[352 + tid];
        dice = 1.f - (2.f * I + SMOOTH) / (G + P + SMOOTH);
        cnt  = G;
    }
    dice = wave_reduce_sum(dice);
    cnt  = wave_reduce_sum(cnt);

    __shared__ float sd[4], sc[4];
    const int w = tid >> 6, l = tid & 63;
    if (l == 0) { sd[w] = dice; sc[w] = cnt; }
    __syncthreads();
    if (tid == 0) {
        const float D  = sd[0] + sd[1] + sd[2] + sd[3];
        const float Cn = sc[0] + sc[1] + sc[2] + sc[3];
        const float ce = ws[528] / fmaxf(Cn, 1.0f);
        out[0] = 0.4f * ce + 0.6f * (D / 176.f);
    }
}

extern "C" void kernel_launch(void* const* d_in, const int* in_sizes, int n_in,
                              void* d_out, int out_size, void* d_ws, size_t ws_size,
                              hipStream_t stream) {
    const float* pred = (const float*)d_in[0];
    const int*   tgt  = (const int*)d_in[1];
    float* ws = (float*)d_ws;

    (void)hipMemsetAsync(d_ws, 0, WS_FLOATS * sizeof(float), stream);
    seg_loss_main<<<2 * BLOCKS_PER_B, TPB, 0, stream>>>(pred, tgt, ws);
    seg_loss_final<<<1, TPB, 0, stream>>>(ws, (float*)d_out);
}